// Round 1
// baseline (349.762 us; speedup 1.0000x reference)
//
#include <hip/hip_runtime.h>

// VINDy layer: out[B,18] = theta(x)[B,1330] @ (big_xi*mask)[1330,18]
// x = concat(z[B,16], betas[B,2]); theta = all monomials deg<=3 over 18 vars,
// in combinations_with_replacement lexicographic order (c fastest, then b, then a).

constexpr int NVARS  = 18;
constexpr int NOUT   = 18;
constexpr int NROWS  = 131072;
constexpr int PTERMS = 1330;   // 1 + 18 + 171 + 1140

__global__ void prep_w_kernel(const float* __restrict__ xi,
                              const float* __restrict__ mask,
                              float* __restrict__ w, int n) {
    int i = blockIdx.x * blockDim.x + threadIdx.x;
    if (i < n) w[i] = xi[i] * mask[i];
}

__global__ __launch_bounds__(256) void vindy_kernel(
        const float* __restrict__ z,
        const float* __restrict__ betas,
        const float* __restrict__ w,
        float* __restrict__ out) {
    // x rows staged in LDS, stride 19 (odd) -> lanes t and t+32 share a bank
    // (2-way, free per m136); stride 18 would give 4-way.
    __shared__ float xs[256 * 19];
    const int tid = threadIdx.x;
    const int row = blockIdx.x * 256 + tid;

    float* xr = &xs[tid * 19];
    {
        const float4* z4 = (const float4*)(z + (size_t)row * 16);
        float4 v0 = z4[0];
        float4 v1 = z4[1];
        float4 v2 = z4[2];
        float4 v3 = z4[3];
        xr[0]  = v0.x; xr[1]  = v0.y; xr[2]  = v0.z; xr[3]  = v0.w;
        xr[4]  = v1.x; xr[5]  = v1.y; xr[6]  = v1.z; xr[7]  = v1.w;
        xr[8]  = v2.x; xr[9]  = v2.y; xr[10] = v2.z; xr[11] = v2.w;
        xr[12] = v3.x; xr[13] = v3.y; xr[14] = v3.z; xr[15] = v3.w;
        const float2 b2 = *(const float2*)(betas + (size_t)row * 2);
        xr[16] = b2.x; xr[17] = b2.y;
    }
    // No __syncthreads needed: each thread reads only its own LDS row.

    float acc[NOUT];
    const float* __restrict__ wp = w;   // W row pointer, wave-uniform -> s_load

    // p = 0: constant term (theta = 1)
#pragma unroll
    for (int j = 0; j < NOUT; ++j) acc[j] = wp[j];
    wp += NOUT;

    // degree 1: terms x[a], a = 0..17
    for (int a = 0; a < NVARS; ++a) {
        float t1 = xr[a];
#pragma unroll
        for (int j = 0; j < NOUT; ++j) acc[j] = fmaf(t1, wp[j], acc[j]);
        wp += NOUT;
    }

    // degree 2: terms x[a]*x[b], a<=b, lexicographic
    for (int a = 0; a < NVARS; ++a) {
        float xa = xr[a];
#pragma unroll 2
        for (int b = a; b < NVARS; ++b) {
            float t2 = xa * xr[b];
#pragma unroll
            for (int j = 0; j < NOUT; ++j) acc[j] = fmaf(t2, wp[j], acc[j]);
            wp += NOUT;
        }
    }

    // degree 3: terms x[a]*x[b]*x[c], a<=b<=c, lexicographic (c fastest)
    for (int a = 0; a < NVARS; ++a) {
        float xa = xr[a];
        for (int b = a; b < NVARS; ++b) {
            float xab = xa * xr[b];
#pragma unroll 2
            for (int c = b; c < NVARS; ++c) {
                float t3 = xab * xr[c];
#pragma unroll
                for (int j = 0; j < NOUT; ++j) acc[j] = fmaf(t3, wp[j], acc[j]);
                wp += NOUT;
            }
        }
    }

    // store 18 floats = 9 float2 (row*72 bytes is 8B-aligned for all rows)
    float2* o2 = (float2*)(out + (size_t)row * NOUT);
#pragma unroll
    for (int j = 0; j < 9; ++j) o2[j] = make_float2(acc[2 * j], acc[2 * j + 1]);
}

extern "C" void kernel_launch(void* const* d_in, const int* in_sizes, int n_in,
                              void* d_out, int out_size, void* d_ws, size_t ws_size,
                              hipStream_t stream) {
    const float* z     = (const float*)d_in[0];
    const float* betas = (const float*)d_in[1];
    const float* xi    = (const float*)d_in[2];
    const float* mask  = (const float*)d_in[3];
    float* w   = (float*)d_ws;           // 1330*18*4 = 95.76 KB scratch
    float* out = (float*)d_out;

    const int n = PTERMS * NOUT;
    prep_w_kernel<<<(n + 255) / 256, 256, 0, stream>>>(xi, mask, w, n);
    vindy_kernel<<<NROWS / 256, 256, 0, stream>>>(z, betas, w, out);
}

// Round 2
// 119.674 us; speedup vs baseline: 2.9226x; 2.9226x over previous
//
#include <hip/hip_runtime.h>
#include <hip/hip_bf16.h>
#include <utility>

// out[131072,18] = theta(x)[131072,1330] @ (xi*mask)[1330,18]
// Reformulated as bf16 MFMA GEMM: K padded 1330->1344 (84 chunks of 16),
// N padded 18->32. A (theta) fragments generated in registers per lane with
// compile-time monomial indices; B (W) pre-swizzled to fragment order in d_ws.

constexpr int NVARS   = 18;
constexpr int NOUT    = 18;
constexpr int NROWS   = 131072;
constexpr int PTERMS  = 1330;
constexpr int NCHUNKS = 84;     // 84 * 16 = 1344 >= 1330

typedef __attribute__((ext_vector_type(8)))  short short8;
typedef __attribute__((ext_vector_type(16))) float f32x16;

struct Term { int a, b, c; };   // 18 = "missing factor" (1.0), 19 = padding (0.0)

constexpr Term term_of(int p) {
    if (p >= PTERMS) return Term{19, 19, 19};
    if (p == 0)      return Term{18, 18, 18};
    int idx = 1;
    for (int a = 0; a < NVARS; ++a) { if (idx == p) return Term{a, 18, 18}; ++idx; }
    for (int a = 0; a < NVARS; ++a)
        for (int b = a; b < NVARS; ++b) { if (idx == p) return Term{a, b, 18}; ++idx; }
    for (int a = 0; a < NVARS; ++a)
        for (int b = a; b < NVARS; ++b)
            for (int c = b; c < NVARS; ++c) { if (idx == p) return Term{a, b, c}; ++idx; }
    return Term{19, 19, 19};
}

template <int P>
__device__ __forceinline__ float term_val(const float (&x)[NVARS]) {
    constexpr Term t = term_of(P);
    if constexpr (t.a >= 19)      return 0.0f;               // K padding
    else if constexpr (t.a == 18) return 1.0f;               // constant term
    else if constexpr (t.b == 18) return x[t.a];             // degree 1
    else if constexpr (t.c == 18) return x[t.a] * x[t.b];    // degree 2
    else                          return x[t.a] * x[t.b] * x[t.c]; // degree 3
}

// Pack two f32 -> bf16x2 (round-half-up via +0x8000, then v_perm byte-select).
__device__ __forceinline__ unsigned pack2(float f0, float f1) {
    unsigned u0 = __float_as_uint(f0) + 0x8000u;
    unsigned u1 = __float_as_uint(f1) + 0x8000u;
    return __builtin_amdgcn_perm(u1, u0, 0x07060302u);  // (u0>>16) | (u1 & 0xFFFF0000)
}

template <int BASE, int... I>
__device__ __forceinline__ void eval16_impl(const float (&x)[NVARS], float (&t)[16],
                                            std::integer_sequence<int, I...>) {
    ((t[I] = term_val<BASE + I>(x)), ...);
}

union AFrag { unsigned u[4]; short8 v; };

template <int CI>
__device__ __forceinline__ void kstep(const float (&x)[NVARS], bool hp,
                                      const short* __restrict__ wlane, f32x16& acc) {
    float t[16];
    eval16_impl<CI * 16>(x, t, std::make_integer_sequence<int, 16>{});
    AFrag af;
#pragma unroll
    for (int j = 0; j < 4; ++j) {
        unsigned lo = pack2(t[2 * j],     t[2 * j + 1]);   // k = 0..7  (half 0)
        unsigned hi = pack2(t[8 + 2 * j], t[8 + 2 * j + 1]); // k = 8..15 (half 1)
        af.u[j] = hp ? hi : lo;
    }
    short8 bf = *(const short8*)(wlane + CI * 512);  // pre-swizzled frag, 1KB/chunk
    acc = __builtin_amdgcn_mfma_f32_32x32x16_bf16(af.v, bf, acc, 0, 0, 0);
}

template <int... CI>
__device__ __forceinline__ void kloop(const float (&x)[NVARS], bool hp,
                                      const short* __restrict__ wlane, f32x16& acc,
                                      std::integer_sequence<int, CI...>) {
    (kstep<CI>(x, hp, wlane, acc), ...);
}

// Prep: W fragments in exact B-operand order. wf[(c*64 + lane)*8 + j] =
// bf16( W[p = c*16 + (lane>>5)*8 + j][n = lane&31] ), zero-padded.
__global__ void prep_wfrag(const float* __restrict__ xi, const float* __restrict__ mask,
                           __hip_bfloat16* __restrict__ wf) {
    int i = blockIdx.x * blockDim.x + threadIdx.x;
    if (i >= NCHUNKS * 64 * 8) return;
    int j = i & 7;
    int l = (i >> 3) & 63;
    int c = i >> 9;
    int p = c * 16 + ((l >> 5) * 8) + j;
    int n = l & 31;
    float v = 0.0f;
    if (p < PTERMS && n < NOUT) v = xi[p * NOUT + n] * mask[p * NOUT + n];
    wf[i] = __float2bfloat16(v);
}

__global__ __launch_bounds__(256) void vindy_mfma(const float* __restrict__ z,
                                                  const float* __restrict__ betas,
                                                  const short* __restrict__ wf,
                                                  float* __restrict__ out) {
    const int lane = threadIdx.x & 63;
    const int wave = threadIdx.x >> 6;
    const int m    = lane & 31;        // batch row within wave tile / A-frag m
    const int half = lane >> 5;        // k-half selector
    const int row  = blockIdx.x * 128 + wave * 32 + m;

    float x[NVARS];
    {
        const float4* z4 = (const float4*)(z + (size_t)row * 16);
        float4 v0 = z4[0], v1 = z4[1], v2 = z4[2], v3 = z4[3];
        x[0]  = v0.x; x[1]  = v0.y; x[2]  = v0.z; x[3]  = v0.w;
        x[4]  = v1.x; x[5]  = v1.y; x[6]  = v1.z; x[7]  = v1.w;
        x[8]  = v2.x; x[9]  = v2.y; x[10] = v2.z; x[11] = v2.w;
        x[12] = v3.x; x[13] = v3.y; x[14] = v3.z; x[15] = v3.w;
        const float2 b2 = *(const float2*)(betas + (size_t)row * 2);
        x[16] = b2.x; x[17] = b2.y;
    }

    f32x16 acc;
#pragma unroll
    for (int i = 0; i < 16; ++i) acc[i] = 0.0f;

    const short* wlane = wf + lane * 8;
    const bool hp = (half != 0);
    kloop(x, hp, wlane, acc, std::make_integer_sequence<int, NCHUNKS>{});

    // C/D layout (32x32): col = lane&31, row = (reg&3) + 8*(reg>>2) + 4*half
    if (m < NOUT) {
        float* op = out + ((size_t)(blockIdx.x * 128 + wave * 32 + half * 4)) * NOUT + m;
#pragma unroll
        for (int r = 0; r < 16; ++r) {
            int rr = (r & 3) + 8 * (r >> 2);
            op[(size_t)rr * NOUT] = acc[r];
        }
    }
}

extern "C" void kernel_launch(void* const* d_in, const int* in_sizes, int n_in,
                              void* d_out, int out_size, void* d_ws, size_t ws_size,
                              hipStream_t stream) {
    const float* z     = (const float*)d_in[0];
    const float* betas = (const float*)d_in[1];
    const float* xi    = (const float*)d_in[2];
    const float* mask  = (const float*)d_in[3];
    __hip_bfloat16* wf = (__hip_bfloat16*)d_ws;   // 84*64*8*2 = 86016 bytes
    float* out = (float*)d_out;

    const int nprep = NCHUNKS * 64 * 8;
    prep_wfrag<<<(nprep + 255) / 256, 256, 0, stream>>>(xi, mask, wf);
    vindy_mfma<<<NROWS / 128, 256, 0, stream>>>(z, betas, (const short*)d_ws, out);
}

// Round 3
// 94.924 us; speedup vs baseline: 3.6847x; 1.2607x over previous
//
#include <hip/hip_runtime.h>
#include <hip/hip_bf16.h>
#include <utility>

// out[131072,18] = theta(x)[131072,1330] @ (xi*mask)[1330,18]
// bf16 MFMA GEMM, K padded 1330->1344 (84 chunks of 16), N padded 18->32.
// sigma-symmetry: terms partitioned into orbits of the involution
// sigma(v)=(v+9)%18; half-0 k-slots hold orbit reps, half-1 slots hold
// sigma(rep). Every lane evaluates the SAME compile-time expressions; half-1
// lanes use permuted inputs x'[v]=x[sigma(v)]. Invariant reps get zero
// weights in the duplicate half-1 slot.

constexpr int NVARS   = 18;
constexpr int NOUT    = 18;
constexpr int NROWS   = 131072;
constexpr int PTERMS  = 1330;
constexpr int NSLOTS  = 672;    // 84 chunks * 8 slots/half
constexpr int NREPS   = 670;    // 1 + 9 + 90 + 570
constexpr int NCHUNKS = 84;

typedef __attribute__((ext_vector_type(8)))  short short8;
typedef __attribute__((ext_vector_type(16))) float f32x16;

struct T3 { int a, b, c; };   // factors sorted ascending; 18 = unused; 19 = pad

constexpr int sig(int v) { return v < 18 ? (v + 9) % 18 : v; }

constexpr T3 sigma3(T3 t) {
    int u0 = sig(t.a), u1 = sig(t.b), u2 = sig(t.c);
    int tmp = 0;
    if (u0 > u1) { tmp = u0; u0 = u1; u1 = tmp; }
    if (u1 > u2) { tmp = u1; u1 = u2; u2 = tmp; }
    if (u0 > u1) { tmp = u0; u0 = u1; u1 = tmp; }
    return T3{u0, u1, u2};
}

constexpr bool t3_less(T3 x, T3 y) {
    if (x.a != y.a) return x.a < y.a;
    if (x.b != y.b) return x.b < y.b;
    return x.c < y.c;
}
constexpr bool t3_eq(T3 x, T3 y) { return x.a == y.a && x.b == y.b && x.c == y.c; }

constexpr int rank_of(T3 t) {
    int deg = (t.a < 18) + (t.b < 18) + (t.c < 18);
    if (deg == 0) return 0;
    if (deg == 1) return 1 + t.a;
    if (deg == 2) {
        int r = 19;
        for (int a = 0; a < t.a; ++a) r += 18 - a;
        return r + (t.b - t.a);
    }
    int r = 190;
    for (int a = 0; a < t.a; ++a) { int n = 18 - a; r += n * (n + 1) / 2; }
    for (int b = t.a; b < t.b; ++b) r += 18 - b;
    return r + (t.c - t.b);
}

struct RepTables {
    signed char va[NSLOTS], vb[NSLOTS], vc[NSLOTS];
    short p0[NSLOTS], p1[NSLOTS];   // flat term index per half; -1 => zero weights
};

constexpr RepTables make_tables() {
    RepTables R{};
    int s = 0;
    // canonical enumeration, keep reps (sigma(t) >= t)
    // deg 0
    {
        T3 t{18, 18, 18};
        R.va[s] = 18; R.vb[s] = 18; R.vc[s] = 18;
        R.p0[s] = 0; R.p1[s] = -1;   // invariant
        ++s;
    }
    for (int a = 0; a < NVARS; ++a) {
        T3 t{a, 18, 18};
        T3 st = sigma3(t);
        if (!t3_less(st, t)) {
            R.va[s] = (signed char)a; R.vb[s] = 18; R.vc[s] = 18;
            R.p0[s] = (short)rank_of(t);
            R.p1[s] = t3_eq(st, t) ? (short)-1 : (short)rank_of(st);
            ++s;
        }
    }
    for (int a = 0; a < NVARS; ++a)
        for (int b = a; b < NVARS; ++b) {
            T3 t{a, b, 18};
            T3 st = sigma3(t);
            if (!t3_less(st, t)) {
                R.va[s] = (signed char)a; R.vb[s] = (signed char)b; R.vc[s] = 18;
                R.p0[s] = (short)rank_of(t);
                R.p1[s] = t3_eq(st, t) ? (short)-1 : (short)rank_of(st);
                ++s;
            }
        }
    for (int a = 0; a < NVARS; ++a)
        for (int b = a; b < NVARS; ++b)
            for (int c = b; c < NVARS; ++c) {
                T3 t{a, b, c};
                T3 st = sigma3(t);
                if (!t3_less(st, t)) {
                    R.va[s] = (signed char)a; R.vb[s] = (signed char)b; R.vc[s] = (signed char)c;
                    R.p0[s] = (short)rank_of(t);
                    R.p1[s] = t3_eq(st, t) ? (short)-1 : (short)rank_of(st);
                    ++s;
                }
            }
    for (; s < NSLOTS; ++s) {       // padding
        R.va[s] = 19; R.vb[s] = 19; R.vc[s] = 19;
        R.p0[s] = -1; R.p1[s] = -1;
    }
    return R;
}

constexpr RepTables h_tab = make_tables();          // compile-time use (templates)
__device__ const RepTables d_tab = make_tables();   // runtime use (prep kernel)

// ---- main kernel -----------------------------------------------------------

__device__ __forceinline__ unsigned pack2(float f0, float f1) {
    unsigned u0 = __float_as_uint(f0) + 0x8000u;
    unsigned u1 = __float_as_uint(f1) + 0x8000u;
    return __builtin_amdgcn_perm(u1, u0, 0x07060302u);
}

template <int S>
__device__ __forceinline__ float term_val(const float (&x)[NVARS]) {
    constexpr int a = h_tab.va[S], b = h_tab.vb[S], c = h_tab.vc[S];
    if constexpr (a >= 19)      return 0.0f;                 // pad
    else if constexpr (a == 18) return 1.0f;                 // constant
    else if constexpr (b == 18) return x[a];
    else if constexpr (c == 18) return x[a] * x[b];
    else                        return x[a] * x[b] * x[c];
}

union AFrag { unsigned u[4]; short8 v; };

template <int CI, int... I>
__device__ __forceinline__ void eval8(const float (&x)[NVARS], float (&t)[8],
                                      std::integer_sequence<int, I...>) {
    ((t[I] = term_val<CI * 8 + I>(x)), ...);
}

template <int CI>
__device__ __forceinline__ void kstep(const float (&x)[NVARS],
                                      const short* __restrict__ wlane, f32x16& acc) {
    float t[8];
    eval8<CI>(x, t, std::make_integer_sequence<int, 8>{});
    AFrag af;
#pragma unroll
    for (int j = 0; j < 4; ++j) af.u[j] = pack2(t[2 * j], t[2 * j + 1]);
    short8 bf = *(const short8*)(wlane + CI * 512);
    acc = __builtin_amdgcn_mfma_f32_32x32x16_bf16(af.v, bf, acc, 0, 0, 0);
}

template <int... CI>
__device__ __forceinline__ void kloop(const float (&x)[NVARS],
                                      const short* __restrict__ wlane, f32x16& acc,
                                      std::integer_sequence<int, CI...>) {
    (kstep<CI>(x, wlane, acc), ...);
}

__global__ __launch_bounds__(256, 4) void vindy_mfma(const float* __restrict__ z,
                                                     const float* __restrict__ betas,
                                                     const short* __restrict__ wf,
                                                     float* __restrict__ out) {
    const int lane = threadIdx.x & 63;
    const int wave = threadIdx.x >> 6;
    const int m    = lane & 31;
    const int half = lane >> 5;
    const int row  = blockIdx.x * 128 + wave * 32 + m;

    float xr[NVARS];
    {
        const float4* z4 = (const float4*)(z + (size_t)row * 16);
        float4 v0 = z4[0], v1 = z4[1], v2 = z4[2], v3 = z4[3];
        xr[0]  = v0.x; xr[1]  = v0.y; xr[2]  = v0.z; xr[3]  = v0.w;
        xr[4]  = v1.x; xr[5]  = v1.y; xr[6]  = v1.z; xr[7]  = v1.w;
        xr[8]  = v2.x; xr[9]  = v2.y; xr[10] = v2.z; xr[11] = v2.w;
        xr[12] = v3.x; xr[13] = v3.y; xr[14] = v3.z; xr[15] = v3.w;
        const float2 b2 = *(const float2*)(betas + (size_t)row * 2);
        xr[16] = b2.x; xr[17] = b2.y;
    }
    // half==1 lanes evaluate rep expressions on sigma-permuted inputs
    const bool hp = (half != 0);
    float x[NVARS];
#pragma unroll
    for (int v = 0; v < NVARS; ++v) x[v] = hp ? xr[(v + 9) % NVARS] : xr[v];

    f32x16 acc;
#pragma unroll
    for (int i = 0; i < 16; ++i) acc[i] = 0.0f;

    const short* wlane = wf + lane * 8;
    kloop(x, wlane, acc, std::make_integer_sequence<int, NCHUNKS>{});

    // C/D layout (32x32): col n = lane&31, row = (reg&3) + 8*(reg>>2) + 4*half
    if (m < NOUT) {
        float* op = out + ((size_t)(blockIdx.x * 128 + wave * 32 + half * 4)) * NOUT + m;
#pragma unroll
        for (int r = 0; r < 16; ++r) {
            int rr = (r & 3) + 8 * (r >> 2);
            op[(size_t)rr * NOUT] = acc[r];
        }
    }
}

// ---- prep: W fragments in B-operand order ----------------------------------
// wf[(c*64 + l)*8 + j]: l = n + 32*h; slot s = c*8+j; term = (h ? sigma(rep) : rep)

__global__ void prep_wfrag(const float* __restrict__ xi, const float* __restrict__ mask,
                           __hip_bfloat16* __restrict__ wf) {
    int i = blockIdx.x * blockDim.x + threadIdx.x;
    if (i >= NCHUNKS * 64 * 8) return;
    int j = i & 7;
    int l = (i >> 3) & 63;
    int c = i >> 9;
    int s = c * 8 + j;
    int n = l & 31;
    int h = l >> 5;
    int p = h ? (int)d_tab.p1[s] : (int)d_tab.p0[s];
    float v = 0.0f;
    if (p >= 0 && n < NOUT) v = xi[p * NOUT + n] * mask[p * NOUT + n];
    wf[i] = __float2bfloat16(v);
}

extern "C" void kernel_launch(void* const* d_in, const int* in_sizes, int n_in,
                              void* d_out, int out_size, void* d_ws, size_t ws_size,
                              hipStream_t stream) {
    const float* z     = (const float*)d_in[0];
    const float* betas = (const float*)d_in[1];
    const float* xi    = (const float*)d_in[2];
    const float* mask  = (const float*)d_in[3];
    __hip_bfloat16* wf = (__hip_bfloat16*)d_ws;   // 84*64*8*2 = 86016 bytes
    float* out = (float*)d_out;

    const int nprep = NCHUNKS * 64 * 8;
    prep_wfrag<<<(nprep + 255) / 256, 256, 0, stream>>>(xi, mask, wf);
    vindy_mfma<<<NROWS / 128, 256, 0, stream>>>(z, betas, (const short*)d_ws, out);
}

// Round 5
// 92.822 us; speedup vs baseline: 3.7681x; 1.0226x over previous
//
#include <hip/hip_runtime.h>
#include <hip/hip_bf16.h>
#include <utility>

// out[131072,18] = theta(x)[131072,1330] @ (xi*mask)[1330,18]
// bf16 MFMA GEMM via mfma_f32_16x16x32_bf16, two N-tiles (cols 0-15, 16-31).
// Order-4 symmetry: rho = (0 1 2 3)(4 5 6 7)(8 9 10 11)(12 13 14 15)(16 17).
// 1330 monomials = 324 size-4 orbits + 16 size-2 + 2 invariant = 342 rep slots
// -> 43 K-chunks of 32. Lane-quad g (lane>>4) evaluates the same compile-time
// rep expressions on rho^g-permuted inputs; duplicate k-positions get zero
// weights. Every lane does unique useful work; theta never materialized.

constexpr int NVARS   = 18;
constexpr int NOUT    = 18;
constexpr int NROWS   = 131072;
constexpr int PTERMS  = 1330;
constexpr int NCHUNKS = 43;             // K = 43*32 = 1376
constexpr int NSLOTS  = NCHUNKS * 8;    // 344 (342 used + 2 pad)

typedef __attribute__((ext_vector_type(8))) short short8;
typedef __attribute__((ext_vector_type(4))) float f32x4;

struct T3 { int a, b, c; };   // sorted ascending; 18 = unused factor; 19 = pad

constexpr int rho1(int v) {
    if (v < 16)  return (v & ~3) | ((v + 1) & 3);
    if (v == 16) return 17;
    if (v == 17) return 16;
    return v;
}
constexpr int rho2v(int v) { return rho1(rho1(v)); }

constexpr T3 sort3(int u0, int u1, int u2) {
    int t = 0;
    if (u0 > u1) { t = u0; u0 = u1; u1 = t; }
    if (u1 > u2) { t = u1; u1 = u2; u2 = t; }
    if (u0 > u1) { t = u0; u0 = u1; u1 = t; }
    return T3{u0, u1, u2};
}
constexpr T3 rho3(T3 t) { return sort3(rho1(t.a), rho1(t.b), rho1(t.c)); }

constexpr bool t3_less(T3 x, T3 y) {
    if (x.a != y.a) return x.a < y.a;
    if (x.b != y.b) return x.b < y.b;
    return x.c < y.c;
}
constexpr bool t3_eq(T3 x, T3 y) { return x.a == y.a && x.b == y.b && x.c == y.c; }

constexpr int rank_of(T3 t) {
    int deg = (t.a < 18) + (t.b < 18) + (t.c < 18);
    if (deg == 0) return 0;
    if (deg == 1) return 1 + t.a;
    if (deg == 2) {
        int r = 19;
        for (int a = 0; a < t.a; ++a) r += 18 - a;
        return r + (t.b - t.a);
    }
    int r = 190;
    for (int a = 0; a < t.a; ++a) { int n = 18 - a; r += n * (n + 1) / 2; }
    for (int b = t.a; b < t.b; ++b) r += 18 - b;
    return r + (t.c - t.b);
}

struct RepTables {
    signed char va[NSLOTS], vb[NSLOTS], vc[NSLOTS];
    short p[4][NSLOTS];   // flat term index for group g's k-position; -1 => zero W
    int count;
};

// C++17 constexpr: every local must be initialized.
constexpr void consider(RepTables& R, int& s, T3 t) {
    T3 im[4] = {t, T3{0, 0, 0}, T3{0, 0, 0}, T3{0, 0, 0}};
    im[1] = rho3(im[0]);
    im[2] = rho3(im[1]);
    im[3] = rho3(im[2]);
    for (int g = 1; g < 4; ++g)
        if (t3_less(im[g], t)) return;   // not the orbit representative
    R.va[s] = (signed char)t.a; R.vb[s] = (signed char)t.b; R.vc[s] = (signed char)t.c;
    for (int g = 0; g < 4; ++g) {
        bool dup = false;
        for (int h = 0; h < g; ++h)
            if (t3_eq(im[h], im[g])) dup = true;
        R.p[g][s] = dup ? (short)-1 : (short)rank_of(im[g]);
    }
    ++s;
}

constexpr RepTables make_tables() {
    RepTables R{};
    int s = 0;
    consider(R, s, T3{18, 18, 18});
    for (int a = 0; a < NVARS; ++a) consider(R, s, T3{a, 18, 18});
    for (int a = 0; a < NVARS; ++a)
        for (int b = a; b < NVARS; ++b) consider(R, s, T3{a, b, 18});
    for (int a = 0; a < NVARS; ++a)
        for (int b = a; b < NVARS; ++b)
            for (int c = b; c < NVARS; ++c) consider(R, s, T3{a, b, c});
    R.count = s;
    for (; s < NSLOTS; ++s) {
        R.va[s] = 19; R.vb[s] = 19; R.vc[s] = 19;
        for (int g = 0; g < 4; ++g) R.p[g][s] = -1;
    }
    return R;
}

constexpr RepTables h_tab = make_tables();          // compile-time use
static_assert(h_tab.count == 342, "orbit enumeration must give 342 rep slots");
__device__ const RepTables d_tab = make_tables();   // runtime use (prep)

// ---- bf16 pair pack --------------------------------------------------------

#if __has_builtin(__builtin_amdgcn_cvt_pk_bf16_f32)
typedef __bf16 bf16x2 __attribute__((ext_vector_type(2)));
__device__ __forceinline__ unsigned pack2(float f0, float f1) {
    bf16x2 r = __builtin_amdgcn_cvt_pk_bf16_f32(f0, f1);   // lo=f0, hi=f1, RNE
    return __builtin_bit_cast(unsigned, r);
}
#else
__device__ __forceinline__ unsigned pack2(float f0, float f1) {
    unsigned u0 = __float_as_uint(f0) + 0x8000u;
    unsigned u1 = __float_as_uint(f1) + 0x8000u;
    return __builtin_amdgcn_perm(u1, u0, 0x07060302u);     // lo=bf16(f0), hi=bf16(f1)
}
#endif

// ---- main kernel -----------------------------------------------------------

template <int S>
__device__ __forceinline__ float term_val(const float (&x)[NVARS]) {
    constexpr int a = h_tab.va[S], b = h_tab.vb[S], c = h_tab.vc[S];
    if constexpr (a >= 19)      return 0.0f;                 // pad slot
    else if constexpr (a == 18) return 1.0f;                 // constant
    else if constexpr (b == 18) return x[a];
    else if constexpr (c == 18) return x[a] * x[b];
    else                        return x[a] * x[b] * x[c];
}

union AFrag { unsigned u[4]; short8 v; };

template <int CI, int... I>
__device__ __forceinline__ void eval8(const float (&x)[NVARS], float (&t)[8],
                                      std::integer_sequence<int, I...>) {
    ((t[I] = term_val<CI * 8 + I>(x)), ...);
}

template <int CI>
__device__ __forceinline__ void kstep(const float (&x)[NVARS],
                                      const short* __restrict__ wlane,
                                      f32x4& acc0, f32x4& acc1) {
    float t[8];
    eval8<CI>(x, t, std::make_integer_sequence<int, 8>{});
    AFrag af;
#pragma unroll
    for (int j = 0; j < 4; ++j) af.u[j] = pack2(t[2 * j], t[2 * j + 1]);
    short8 b0 = *(const short8*)(wlane + (CI * 2 + 0) * 512);
    short8 b1 = *(const short8*)(wlane + (CI * 2 + 1) * 512);
    acc0 = __builtin_amdgcn_mfma_f32_16x16x32_bf16(af.v, b0, acc0, 0, 0, 0);
    acc1 = __builtin_amdgcn_mfma_f32_16x16x32_bf16(af.v, b1, acc1, 0, 0, 0);
}

template <int... CI>
__device__ __forceinline__ void kloop(const float (&x)[NVARS],
                                      const short* __restrict__ wlane,
                                      f32x4& acc0, f32x4& acc1,
                                      std::integer_sequence<int, CI...>) {
    (kstep<CI>(x, wlane, acc0, acc1), ...);
}

__global__ __launch_bounds__(256, 5) void vindy_mfma(const float* __restrict__ z,
                                                     const float* __restrict__ betas,
                                                     const short* __restrict__ wf,
                                                     float* __restrict__ out) {
    const int lane = threadIdx.x & 63;
    const int wave = threadIdx.x >> 6;
    const int g    = lane >> 4;        // rho-power / k-quad
    const int mcol = lane & 15;        // A-row for input load; C col for store
    const int rowbase = blockIdx.x * 64 + wave * 16;
    const int arow = rowbase + mcol;

    float x0[NVARS];
    {
        const float4* z4 = (const float4*)(z + (size_t)arow * 16);
        float4 v0 = z4[0], v1 = z4[1], v2 = z4[2], v3 = z4[3];
        x0[0]  = v0.x; x0[1]  = v0.y; x0[2]  = v0.z; x0[3]  = v0.w;
        x0[4]  = v1.x; x0[5]  = v1.y; x0[6]  = v1.z; x0[7]  = v1.w;
        x0[8]  = v2.x; x0[9]  = v2.y; x0[10] = v2.z; x0[11] = v2.w;
        x0[12] = v3.x; x0[13] = v3.y; x0[14] = v3.z; x0[15] = v3.w;
        const float2 b2 = *(const float2*)(betas + (size_t)arow * 2);
        x0[16] = b2.x; x0[17] = b2.y;
    }
    // x[v] = x0[rho^g(v)] via two select stages (compile-time rho indices)
    const bool s1 = (g & 1) != 0;
    const bool s2 = (g & 2) != 0;
    float y[NVARS], x[NVARS];
#pragma unroll
    for (int v = 0; v < NVARS; ++v) y[v] = s1 ? x0[rho1(v)] : x0[v];
#pragma unroll
    for (int v = 0; v < NVARS; ++v) x[v] = s2 ? y[rho2v(v)] : y[v];

    f32x4 acc0, acc1;
#pragma unroll
    for (int i = 0; i < 4; ++i) { acc0[i] = 0.0f; acc1[i] = 0.0f; }

    const short* wlane = wf + lane * 8;
    kloop(x, wlane, acc0, acc1, std::make_integer_sequence<int, NCHUNKS>{});

    // C/D 16x16 layout: col n = lane&15, row m = (lane>>4)*4 + reg
    const int orow = rowbase + g * 4;
    float* op0 = out + (size_t)orow * NOUT + mcol;
#pragma unroll
    for (int r = 0; r < 4; ++r) op0[(size_t)r * NOUT] = acc0[r];
    if (mcol < NOUT - 16) {
        float* op1 = out + (size_t)orow * NOUT + 16 + mcol;
#pragma unroll
        for (int r = 0; r < 4; ++r) op1[(size_t)r * NOUT] = acc1[r];
    }
}

// ---- prep: W fragments in B-operand order ----------------------------------
// wf[((c*2+T)*64 + l)*8 + j] = bf16(W[p][n]); g=l>>4, n=T*16+(l&15),
// p = d_tab.p[g][c*8+j] (-1 or n>=18 -> 0).

__global__ void prep_wfrag(const float* __restrict__ xi, const float* __restrict__ mask,
                           __hip_bfloat16* __restrict__ wf) {
    int i = blockIdx.x * blockDim.x + threadIdx.x;
    if (i >= NCHUNKS * 2 * 64 * 8) return;
    int j  = i & 7;
    int l  = (i >> 3) & 63;
    int ct = i >> 9;          // c*2 + T
    int c  = ct >> 1;
    int T  = ct & 1;
    int gg = l >> 4;
    int n  = T * 16 + (l & 15);
    int s  = c * 8 + j;
    int p  = (int)d_tab.p[gg][s];
    float v = 0.0f;
    if (p >= 0 && n < NOUT) v = xi[p * NOUT + n] * mask[p * NOUT + n];
    wf[i] = __float2bfloat16(v);
}

extern "C" void kernel_launch(void* const* d_in, const int* in_sizes, int n_in,
                              void* d_out, int out_size, void* d_ws, size_t ws_size,
                              hipStream_t stream) {
    const float* z     = (const float*)d_in[0];
    const float* betas = (const float*)d_in[1];
    const float* xi    = (const float*)d_in[2];
    const float* mask  = (const float*)d_in[3];
    __hip_bfloat16* wf = (__hip_bfloat16*)d_ws;   // 43*2*64*8*2 = 88064 bytes
    float* out = (float*)d_out;

    const int nprep = NCHUNKS * 2 * 64 * 8;
    prep_wfrag<<<(nprep + 255) / 256, 256, 0, stream>>>(xi, mask, wf);
    vindy_mfma<<<NROWS / 64, 256, 0, stream>>>(z, betas, (const short*)d_ws, out);
}

// Round 6
// 90.454 us; speedup vs baseline: 3.8667x; 1.0262x over previous
//
#include <hip/hip_runtime.h>
#include <hip/hip_bf16.h>
#include <utility>

// out[131072,18] = theta(x)[131072,1330] @ (xi*mask)[1330,18]
// bf16 MFMA GEMM via mfma_f32_16x16x32_bf16.
// Order-4 symmetry rho = (0123)(4567)(89AB)(CDEF)(16 17): 1330 monomials ->
// 342 rep slots -> 43 K-chunks of 32. Lane-quad g evaluates the same
// compile-time rep expressions on rho^g-permuted inputs.
// Round-6 structure: W fragments staged in LDS once per block (tile0 full,
// tile1 compressed to its 2 real columns), each wave computes 2 row-tiles
// (32 rows) sharing every B fragment -> L2 B-traffic amortized ~16x.

constexpr int NVARS   = 18;
constexpr int NOUT    = 18;
constexpr int NROWS   = 131072;
constexpr int PTERMS  = 1330;
constexpr int NCHUNKS = 43;             // K = 43*32 = 1376
constexpr int NSLOTS  = NCHUNKS * 8;    // 344 (342 used + 2 pad)

constexpr int WF0_SHORTS = NCHUNKS * 512;   // tile0 frags: 22016 shorts (44032 B)
constexpr int WF1_SHORTS = NCHUNKS * 64;    // compact tile1: 2752 shorts (5504 B)
constexpr int WF_SHORTS  = WF0_SHORTS + WF1_SHORTS;  // 24768 shorts = 49536 B

typedef __attribute__((ext_vector_type(8))) short short8;
typedef __attribute__((ext_vector_type(4))) float f32x4;

struct T3 { int a, b, c; };   // sorted ascending; 18 = unused factor; 19 = pad

constexpr int rho1(int v) {
    if (v < 16)  return (v & ~3) | ((v + 1) & 3);
    if (v == 16) return 17;
    if (v == 17) return 16;
    return v;
}
constexpr int rho2v(int v) { return rho1(rho1(v)); }

constexpr T3 sort3(int u0, int u1, int u2) {
    int t = 0;
    if (u0 > u1) { t = u0; u0 = u1; u1 = t; }
    if (u1 > u2) { t = u1; u1 = u2; u2 = t; }
    if (u0 > u1) { t = u0; u0 = u1; u1 = t; }
    return T3{u0, u1, u2};
}
constexpr T3 rho3(T3 t) { return sort3(rho1(t.a), rho1(t.b), rho1(t.c)); }

constexpr bool t3_less(T3 x, T3 y) {
    if (x.a != y.a) return x.a < y.a;
    if (x.b != y.b) return x.b < y.b;
    return x.c < y.c;
}
constexpr bool t3_eq(T3 x, T3 y) { return x.a == y.a && x.b == y.b && x.c == y.c; }

constexpr int rank_of(T3 t) {
    int deg = (t.a < 18) + (t.b < 18) + (t.c < 18);
    if (deg == 0) return 0;
    if (deg == 1) return 1 + t.a;
    if (deg == 2) {
        int r = 19;
        for (int a = 0; a < t.a; ++a) r += 18 - a;
        return r + (t.b - t.a);
    }
    int r = 190;
    for (int a = 0; a < t.a; ++a) { int n = 18 - a; r += n * (n + 1) / 2; }
    for (int b = t.a; b < t.b; ++b) r += 18 - b;
    return r + (t.c - t.b);
}

struct RepTables {
    signed char va[NSLOTS], vb[NSLOTS], vc[NSLOTS];
    short p[4][NSLOTS];   // flat term index for group g's k-position; -1 => zero W
    int count;
};

constexpr void consider(RepTables& R, int& s, T3 t) {
    T3 im[4] = {t, T3{0, 0, 0}, T3{0, 0, 0}, T3{0, 0, 0}};
    im[1] = rho3(im[0]);
    im[2] = rho3(im[1]);
    im[3] = rho3(im[2]);
    for (int g = 1; g < 4; ++g)
        if (t3_less(im[g], t)) return;   // not the orbit representative
    R.va[s] = (signed char)t.a; R.vb[s] = (signed char)t.b; R.vc[s] = (signed char)t.c;
    for (int g = 0; g < 4; ++g) {
        bool dup = false;
        for (int h = 0; h < g; ++h)
            if (t3_eq(im[h], im[g])) dup = true;
        R.p[g][s] = dup ? (short)-1 : (short)rank_of(im[g]);
    }
    ++s;
}

constexpr RepTables make_tables() {
    RepTables R{};
    int s = 0;
    consider(R, s, T3{18, 18, 18});
    for (int a = 0; a < NVARS; ++a) consider(R, s, T3{a, 18, 18});
    for (int a = 0; a < NVARS; ++a)
        for (int b = a; b < NVARS; ++b) consider(R, s, T3{a, b, 18});
    for (int a = 0; a < NVARS; ++a)
        for (int b = a; b < NVARS; ++b)
            for (int c = b; c < NVARS; ++c) consider(R, s, T3{a, b, c});
    R.count = s;
    for (; s < NSLOTS; ++s) {
        R.va[s] = 19; R.vb[s] = 19; R.vc[s] = 19;
        for (int g = 0; g < 4; ++g) R.p[g][s] = -1;
    }
    return R;
}

constexpr RepTables h_tab = make_tables();          // compile-time use
static_assert(h_tab.count == 342, "orbit enumeration must give 342 rep slots");
__device__ const RepTables d_tab = make_tables();   // runtime use (prep)

// ---- bf16 pair pack --------------------------------------------------------

#if __has_builtin(__builtin_amdgcn_cvt_pk_bf16_f32)
typedef __bf16 bf16x2 __attribute__((ext_vector_type(2)));
__device__ __forceinline__ unsigned pack2(float f0, float f1) {
    bf16x2 r = __builtin_amdgcn_cvt_pk_bf16_f32(f0, f1);   // lo=f0, hi=f1, RNE
    return __builtin_bit_cast(unsigned, r);
}
#else
__device__ __forceinline__ unsigned pack2(float f0, float f1) {
    unsigned u0 = __float_as_uint(f0) + 0x8000u;
    unsigned u1 = __float_as_uint(f1) + 0x8000u;
    return __builtin_amdgcn_perm(u1, u0, 0x07060302u);     // lo=bf16(f0), hi=bf16(f1)
}
#endif

// ---- main kernel -----------------------------------------------------------

template <int S>
__device__ __forceinline__ float term_val(const float (&x)[NVARS]) {
    constexpr int a = h_tab.va[S], b = h_tab.vb[S], c = h_tab.vc[S];
    if constexpr (a >= 19)      return 0.0f;                 // pad slot
    else if constexpr (a == 18) return 1.0f;                 // constant
    else if constexpr (b == 18) return x[a];
    else if constexpr (c == 18) return x[a] * x[b];
    else                        return x[a] * x[b] * x[c];
}

union AFrag { unsigned u[4]; short8 v; };
union BFrag { unsigned u[4]; short8 v; };

template <int CI, int... I>
__device__ __forceinline__ void eval8(const float (&x)[NVARS], float (&t)[8],
                                      std::integer_sequence<int, I...>) {
    ((t[I] = term_val<CI * 8 + I>(x)), ...);
}

template <int CI>
__device__ __forceinline__ void kstep(const float (&xA)[NVARS], const float (&xB)[NVARS],
                                      const short* p0, const short* p1, unsigned zmask,
                                      f32x4& acc00, f32x4& acc01,
                                      f32x4& acc10, f32x4& acc11) {
    float tA[8], tB[8];
    eval8<CI>(xA, tA, std::make_integer_sequence<int, 8>{});
    eval8<CI>(xB, tB, std::make_integer_sequence<int, 8>{});
    AFrag afA, afB;
#pragma unroll
    for (int j = 0; j < 4; ++j) {
        afA.u[j] = pack2(tA[2 * j], tA[2 * j + 1]);
        afB.u[j] = pack2(tB[2 * j], tB[2 * j + 1]);
    }
    short8 b0 = *(const short8*)(p0 + CI * 512);   // tile0 frag, ds_read_b128
    BFrag b1;
    b1.v = *(const short8*)(p1 + CI * 64);         // compact tile1 frag
#pragma unroll
    for (int j = 0; j < 4; ++j) b1.u[j] &= zmask;  // zero for col-lanes n>=2
    acc00 = __builtin_amdgcn_mfma_f32_16x16x32_bf16(afA.v, b0,   acc00, 0, 0, 0);
    acc10 = __builtin_amdgcn_mfma_f32_16x16x32_bf16(afB.v, b0,   acc10, 0, 0, 0);
    acc01 = __builtin_amdgcn_mfma_f32_16x16x32_bf16(afA.v, b1.v, acc01, 0, 0, 0);
    acc11 = __builtin_amdgcn_mfma_f32_16x16x32_bf16(afB.v, b1.v, acc11, 0, 0, 0);
}

template <int... CI>
__device__ __forceinline__ void kloop(const float (&xA)[NVARS], const float (&xB)[NVARS],
                                      const short* p0, const short* p1, unsigned zmask,
                                      f32x4& acc00, f32x4& acc01,
                                      f32x4& acc10, f32x4& acc11,
                                      std::integer_sequence<int, CI...>) {
    (kstep<CI>(xA, xB, p0, p1, zmask, acc00, acc01, acc10, acc11), ...);
}

__device__ __forceinline__ void load_x(const float* __restrict__ z,
                                       const float* __restrict__ betas,
                                       int arow, bool s1, bool s2, float (&x)[NVARS]) {
    float x0[NVARS];
    const float4* z4 = (const float4*)(z + (size_t)arow * 16);
    float4 v0 = z4[0], v1 = z4[1], v2 = z4[2], v3 = z4[3];
    x0[0]  = v0.x; x0[1]  = v0.y; x0[2]  = v0.z; x0[3]  = v0.w;
    x0[4]  = v1.x; x0[5]  = v1.y; x0[6]  = v1.z; x0[7]  = v1.w;
    x0[8]  = v2.x; x0[9]  = v2.y; x0[10] = v2.z; x0[11] = v2.w;
    x0[12] = v3.x; x0[13] = v3.y; x0[14] = v3.z; x0[15] = v3.w;
    const float2 b2 = *(const float2*)(betas + (size_t)arow * 2);
    x0[16] = b2.x; x0[17] = b2.y;
    float y[NVARS];
#pragma unroll
    for (int v = 0; v < NVARS; ++v) y[v] = s1 ? x0[rho1(v)] : x0[v];
#pragma unroll
    for (int v = 0; v < NVARS; ++v) x[v] = s2 ? y[rho2v(v)] : y[v];
}

__global__ __launch_bounds__(256, 4) void vindy_mfma(const float* __restrict__ z,
                                                     const float* __restrict__ betas,
                                                     const short* __restrict__ wf,
                                                     float* __restrict__ out) {
    __shared__ __align__(16) short ldsW[WF_SHORTS];   // 49536 B -> 3 blocks/CU
    // stage all W fragments once per block (flat 16B copies, fully coalesced)
    {
        const float4* src = (const float4*)wf;
        float4* dst = (float4*)ldsW;
        for (int i = threadIdx.x; i < WF_SHORTS / 8; i += 256) dst[i] = src[i];
    }
    __syncthreads();

    const int lane = threadIdx.x & 63;
    const int wave = threadIdx.x >> 6;
    const int g    = lane >> 4;        // rho-power / k-quad
    const int n    = lane & 15;        // A-row within tile; C col
    const int rowbase = blockIdx.x * 128 + wave * 32;

    const bool s1 = (g & 1) != 0;
    const bool s2 = (g & 2) != 0;
    float xA[NVARS], xB[NVARS];
    load_x(z, betas, rowbase + n,      s1, s2, xA);
    load_x(z, betas, rowbase + 16 + n, s1, s2, xB);

    const unsigned zmask = (n < 2) ? 0xFFFFFFFFu : 0u;
    const short* p0 = ldsW + lane * 8;                               // tile0 base
    const short* p1 = ldsW + WF0_SHORTS + (g * 2 + (n < 2 ? n : 0)) * 8; // tile1 base

    f32x4 acc00, acc01, acc10, acc11;
#pragma unroll
    for (int i = 0; i < 4; ++i) { acc00[i] = 0.0f; acc01[i] = 0.0f; acc10[i] = 0.0f; acc11[i] = 0.0f; }

    kloop(xA, xB, p0, p1, zmask, acc00, acc01, acc10, acc11,
          std::make_integer_sequence<int, NCHUNKS>{});

    // C/D 16x16 layout: col = lane&15, row = g*4 + reg
    float* o0 = out + (size_t)(rowbase + g * 4) * NOUT;
    float* o1 = out + (size_t)(rowbase + 16 + g * 4) * NOUT;
#pragma unroll
    for (int r = 0; r < 4; ++r) {
        o0[(size_t)r * NOUT + n] = acc00[r];
        o1[(size_t)r * NOUT + n] = acc10[r];
    }
    if (n < 2) {
#pragma unroll
        for (int r = 0; r < 4; ++r) {
            o0[(size_t)r * NOUT + 16 + n] = acc01[r];
            o1[(size_t)r * NOUT + 16 + n] = acc11[r];
        }
    }
}

// ---- prep: W fragments in staged layout ------------------------------------
// region 0 (tile0, cols 0-15): wf[c*512 + l*8 + j] = W[p[l>>4][c*8+j]][l&15]
// region 1 (tile1 compact):    wf[WF0 + c*64 + (g*2+nn)*8 + j] = W[p[g][c*8+j]][16+nn]

__global__ void prep_wfrag(const float* __restrict__ xi, const float* __restrict__ mask,
                           __hip_bfloat16* __restrict__ wf) {
    int i = blockIdx.x * blockDim.x + threadIdx.x;
    if (i >= WF_SHORTS) return;
    int p = -1, col = 0;
    if (i < WF0_SHORTS) {
        int j = i & 7, l = (i >> 3) & 63, c = i >> 9;
        col = l & 15;
        p = d_tab.p[l >> 4][c * 8 + j];
    } else {
        int i2 = i - WF0_SHORTS;
        int j = i2 & 7, q = (i2 >> 3) & 7, c = i2 >> 6;
        col = 16 + (q & 1);
        p = d_tab.p[q >> 1][c * 8 + j];
    }
    float v = 0.0f;
    if (p >= 0) v = xi[p * NOUT + col] * mask[p * NOUT + col];
    wf[i] = __float2bfloat16(v);
}

extern "C" void kernel_launch(void* const* d_in, const int* in_sizes, int n_in,
                              void* d_out, int out_size, void* d_ws, size_t ws_size,
                              hipStream_t stream) {
    const float* z     = (const float*)d_in[0];
    const float* betas = (const float*)d_in[1];
    const float* xi    = (const float*)d_in[2];
    const float* mask  = (const float*)d_in[3];
    __hip_bfloat16* wf = (__hip_bfloat16*)d_ws;   // 49536 bytes
    float* out = (float*)d_out;

    prep_wfrag<<<(WF_SHORTS + 255) / 256, 256, 0, stream>>>(xi, mask, wf);
    vindy_mfma<<<NROWS / 128, 256, 0, stream>>>(z, betas, (const short*)d_ws, out);
}